// Round 1
// 331.906 us; speedup vs baseline: 1.0295x; 1.0295x over previous
//
#include <hip/hip_runtime.h>
#include <hip/hip_bf16.h>

// GATNet v9: k_agg1 gather widened to dwordx4 (4 edge-slots x 32 col-groups,
// unroll-2 => 8 edges / 32B per thread in flight; VALU/byte -35%, 4x fewer
// load instrs). k_agg2 widened scalar-ushort -> dword with 8 edge slots.
// prepw kernels merged.

#define LRELU(x) ((x) > 0.f ? (x) : 0.2f * (x))

typedef __attribute__((ext_vector_type(8))) short short8;
typedef __attribute__((ext_vector_type(8))) unsigned short ushort8;
typedef __attribute__((ext_vector_type(4))) float f32x4;

__device__ inline unsigned short f2b(float f) {
    __hip_bfloat16 h = __float2bfloat16(f);
    return *reinterpret_cast<unsigned short*>(&h);
}
__device__ inline float b2f(unsigned short u) {
    __hip_bfloat16 h;
    *reinterpret_cast<unsigned short*>(&h) = u;
    return __bfloat162float(h);
}
__device__ inline float bl(unsigned int u) { return __uint_as_float(u << 16); }
__device__ inline float bh(unsigned int u) { return __uint_as_float(u & 0xffff0000u); }

// ---------------- CSR build ----------------

__global__ void k_hist(const int* __restrict__ dst, int* deg, int E) {
    int i = blockIdx.x * blockDim.x + threadIdx.x;
    if (i < E) atomicAdd(&deg[dst[i]], 1);
}

__global__ __launch_bounds__(256) void k_scanA(const int* __restrict__ deg,
                                               int* __restrict__ tmp,
                                               int* __restrict__ blocksum, int n) {
    __shared__ int sc[256];
    int b = blockIdx.x, t = threadIdx.x;
    int i = b * 256 + t;
    int v = (i < n) ? deg[i] + 1 : 0;   // +1: self loop
    sc[t] = v;
    __syncthreads();
    for (int off = 1; off < 256; off <<= 1) {
        int x = 0;
        if (t >= off) x = sc[t - off];
        __syncthreads();
        sc[t] += x;
        __syncthreads();
    }
    if (i < n) tmp[i] = sc[t] - v;
    if (t == 255) blocksum[b] = sc[255];
}

__global__ __launch_bounds__(256) void k_scanB(const int* __restrict__ blocksum,
                                               int* __restrict__ blockpre, int nb) {
    __shared__ int sc[256];
    int t = threadIdx.x;
    int v = (t < nb) ? blocksum[t] : 0;
    sc[t] = v;
    __syncthreads();
    for (int off = 1; off < 256; off <<= 1) {
        int x = 0;
        if (t >= off) x = sc[t - off];
        __syncthreads();
        sc[t] += x;
        __syncthreads();
    }
    if (t < nb) blockpre[t] = sc[t] - v;
}

__global__ __launch_bounds__(256) void k_scanC(const int* __restrict__ tmp,
                                               const int* __restrict__ blockpre,
                                               int* __restrict__ offs,
                                               int* __restrict__ cursor, int n, int P) {
    int b = blockIdx.x, t = threadIdx.x;
    int i = b * 256 + t;
    if (i < n) {
        int o = tmp[i] + blockpre[b];
        offs[i] = o;
        cursor[i] = o;
    }
    if (i == 0) offs[n] = P;
}

__global__ void k_scatter(const int* __restrict__ src, const int* __restrict__ dst,
                          int* cursor, int* __restrict__ csr, int E, int n) {
    int i = blockIdx.x * blockDim.x + threadIdx.x;
    int s, d;
    if (i < E) {
        s = src[i];
        d = dst[i];
    } else if (i < E + n) {
        s = i - E;
        d = s;
    } else {
        return;
    }
    int p = atomicAdd(&cursor[d], 1);
    csr[p] = s;
}

// ---------------- weight prep: W1t[256][256], W2t[16][256] bf16 (merged) ----

__global__ __launch_bounds__(256) void k_prepw(const float* __restrict__ W1,
                                               const float* __restrict__ W2,
                                               unsigned short* __restrict__ W1t,
                                               unsigned short* __restrict__ W2t) {
    int b = blockIdx.x;
    if (b < 256) {
        int k = b, nn = threadIdx.x;
        W1t[nn * 256 + k] = f2b(W1[k * 256 + nn]);
    } else {
        int nn = b - 256, k = threadIdx.x;
        W2t[nn * 256 + k] = f2b(W2[k * 16 + nn]);
    }
}

// ---------------- GEMM1 (MFMA bf16): h1b[M,256] = bf16(A[M,256] @ W1) -------

__global__ __launch_bounds__(256) void k_gemm1(const float* __restrict__ A,
                                               const unsigned short* __restrict__ Wt,
                                               unsigned short* __restrict__ h1b, int M) {
    __shared__ unsigned short As[128][40];
    __shared__ unsigned short Bs[128][40];
    int t = threadIdx.x;
    int r0 = blockIdx.x * 128, c0 = blockIdx.y * 128;
    int srow = t >> 1, shalf = t & 1;
    int lane = t & 63, w = t >> 6;
    int lane15 = lane & 15, quad = lane >> 4;
    int rbw = (w & 1) * 64, cbw = (w >> 1) * 64;

    f32x4 acc[4][4];
#pragma unroll
    for (int i = 0; i < 4; i++)
#pragma unroll
        for (int j = 0; j < 4; j++) acc[i][j] = (f32x4)0.f;

    for (int k0 = 0; k0 < 256; k0 += 32) {
        {
            int row = r0 + srow;
            ushort8 p0, p1;
            if (row < M) {
                const float4* sp = (const float4*)&A[(size_t)row * 256 + k0 + shalf * 16];
                float4 f0 = sp[0], f1 = sp[1], f2 = sp[2], f3 = sp[3];
                p0[0] = f2b(f0.x); p0[1] = f2b(f0.y); p0[2] = f2b(f0.z); p0[3] = f2b(f0.w);
                p0[4] = f2b(f1.x); p0[5] = f2b(f1.y); p0[6] = f2b(f1.z); p0[7] = f2b(f1.w);
                p1[0] = f2b(f2.x); p1[1] = f2b(f2.y); p1[2] = f2b(f2.z); p1[3] = f2b(f2.w);
                p1[4] = f2b(f3.x); p1[5] = f2b(f3.y); p1[6] = f2b(f3.z); p1[7] = f2b(f3.w);
            } else {
                p0 = (ushort8)0; p1 = (ushort8)0;
            }
            *(ushort8*)&As[srow][shalf * 16] = p0;
            *(ushort8*)&As[srow][shalf * 16 + 8] = p1;
            const ushort8* bp = (const ushort8*)&Wt[(size_t)(c0 + srow) * 256 + k0 + shalf * 16];
            *(ushort8*)&Bs[srow][shalf * 16] = bp[0];
            *(ushort8*)&Bs[srow][shalf * 16 + 8] = bp[1];
        }
        __syncthreads();
        short8 af[4], bf[4];
#pragma unroll
        for (int i = 0; i < 4; i++)
            af[i] = *(const short8*)&As[rbw + i * 16 + lane15][quad * 8];
#pragma unroll
        for (int j = 0; j < 4; j++)
            bf[j] = *(const short8*)&Bs[cbw + j * 16 + lane15][quad * 8];
#pragma unroll
        for (int i = 0; i < 4; i++)
#pragma unroll
            for (int j = 0; j < 4; j++)
                acc[i][j] = __builtin_amdgcn_mfma_f32_16x16x32_bf16(af[i], bf[j], acc[i][j], 0, 0, 0);
        __syncthreads();
    }
#pragma unroll
    for (int i = 0; i < 4; i++) {
        int rowb = r0 + rbw + i * 16 + quad * 4;
#pragma unroll
        for (int j = 0; j < 4; j++) {
            int col = c0 + cbw + j * 16 + lane15;
#pragma unroll
            for (int r = 0; r < 4; r++) {
                int row = rowb + r;
                if (row < M) h1b[(size_t)row * 256 + col] = f2b(acc[i][j][r]);
            }
        }
    }
}

// ---------------- attention logits layer 1: wave per node, 4 nodes/block ----

__global__ __launch_bounds__(256) void k_al1(const unsigned short* __restrict__ h1b,
                                             const float* __restrict__ asrc,
                                             const float* __restrict__ adst,
                                             float* __restrict__ als,
                                             float* __restrict__ ald, int n) {
    int v = blockIdx.x * 4 + (threadIdx.x >> 6);
    if (v >= n) return;
    int lane = threadIdx.x & 63;
    const uint2* hp = (const uint2*)(h1b + (size_t)v * 256);
    uint2 pk = hp[lane];
    float f0 = bl(pk.x);
    float f1 = bh(pk.x);
    float f2 = bl(pk.y);
    float f3 = bh(pk.y);
    float4 a_s = ((const float4*)asrc)[lane];
    float4 a_d = ((const float4*)adst)[lane];
    float ps = f0 * a_s.x + f1 * a_s.y + f2 * a_s.z + f3 * a_s.w;
    float pd = f0 * a_d.x + f1 * a_d.y + f2 * a_d.z + f3 * a_d.w;
#pragma unroll
    for (int off = 1; off < 8; off <<= 1) {
        ps += __shfl_xor(ps, off, 64);
        pd += __shfl_xor(pd, off, 64);
    }
    if ((lane & 7) == 0) {
        int h = lane >> 3;
        als[v * 8 + h] = ps;
        ald[v * 8 + h] = pd;
    }
}

// ---------------- layer-1 aggregate: dwordx4 gather, 4 edge-slots -----------
// 128 thr = 4 slots x 32 col-groups. Each thread loads 16B (8 cols) of one
// edge's h1b row per step; unroll 2 => 32B in flight. Slot reduction via
// shfl_xor(32) + LDS, packed dwordx4 bf16 store.

__global__ __launch_bounds__(128) void k_agg1(const int* __restrict__ csr,
                                              const int* __restrict__ offs,
                                              const float* __restrict__ als,
                                              const float* __restrict__ aldg,
                                              const unsigned short* __restrict__ h1b,
                                              const float* __restrict__ b1,
                                              unsigned short* __restrict__ x2b) {
    int v = blockIdx.x;
    int t = threadIdx.x;
    int start = offs[v];
    int deg = offs[v + 1] - start;
    __shared__ float aldv[8];
    __shared__ int su[32];
    __shared__ float ws[8 * 33];
    __shared__ float red[32][9];
    if (t < 8) aldv[t] = aldg[v * 8 + t];
    __syncthreads();
    int slot = t >> 5;       // 0..3 edge slot
    int cg = t & 31;         // 16B col-group: cols 8*cg .. 8*cg+7
    int h = cg >> 2;         // head (32 cols = 4 col-groups)
    const uint4* hb4 = (const uint4*)h1b;   // row = 32 uint4
    float a0 = 0.f, a1 = 0.f, a2 = 0.f, a3 = 0.f;
    float a4 = 0.f, a5 = 0.f, a6 = 0.f, a7 = 0.f;
    float wsum = 0.f;
    for (int base = 0; base < deg; base += 32) {
        int cnt = min(32, deg - base);
        int cnt8 = (cnt + 7) & ~7;      // pad to multiple of 8 (<=32)
        if (base) __syncthreads();
        if (t < cnt8) {
            if (t < cnt) {
                int u = csr[start + base + t];
                su[t] = u;
                const float4* ap = (const float4*)(als + (size_t)u * 8);
                float4 x0 = ap[0], x1 = ap[1];
                ws[0 * 33 + t] = __expf(LRELU(x0.x + aldv[0]));
                ws[1 * 33 + t] = __expf(LRELU(x0.y + aldv[1]));
                ws[2 * 33 + t] = __expf(LRELU(x0.z + aldv[2]));
                ws[3 * 33 + t] = __expf(LRELU(x0.w + aldv[3]));
                ws[4 * 33 + t] = __expf(LRELU(x1.x + aldv[4]));
                ws[5 * 33 + t] = __expf(LRELU(x1.y + aldv[5]));
                ws[6 * 33 + t] = __expf(LRELU(x1.z + aldv[6]));
                ws[7 * 33 + t] = __expf(LRELU(x1.w + aldv[7]));
            } else {
                su[t] = v;   // valid row, weight 0 -> inert
#pragma unroll
                for (int k = 0; k < 8; k++) ws[k * 33 + t] = 0.f;
            }
        }
        __syncthreads();
        for (int e = 0; e < cnt8; e += 8) {
            int u0 = su[e + slot];
            int u1 = su[e + 4 + slot];
            float w0 = ws[h * 33 + e + slot];
            float w1 = ws[h * 33 + e + 4 + slot];
            uint4 p0 = hb4[u0 * 32 + cg];
            uint4 p1 = hb4[u1 * 32 + cg];
            a0 += w0 * bl(p0.x); a1 += w0 * bh(p0.x);
            a2 += w0 * bl(p0.y); a3 += w0 * bh(p0.y);
            a4 += w0 * bl(p0.z); a5 += w0 * bh(p0.z);
            a6 += w0 * bl(p0.w); a7 += w0 * bh(p0.w);
            a0 += w1 * bl(p1.x); a1 += w1 * bh(p1.x);
            a2 += w1 * bl(p1.y); a3 += w1 * bh(p1.y);
            a4 += w1 * bl(p1.z); a5 += w1 * bh(p1.z);
            a6 += w1 * bl(p1.w); a7 += w1 * bh(p1.w);
            wsum += w0 + w1;
        }
    }
    // reduce slot pairs within each wave: (0,1) in wave0, (2,3) in wave1
    a0 += __shfl_xor(a0, 32, 64);
    a1 += __shfl_xor(a1, 32, 64);
    a2 += __shfl_xor(a2, 32, 64);
    a3 += __shfl_xor(a3, 32, 64);
    a4 += __shfl_xor(a4, 32, 64);
    a5 += __shfl_xor(a5, 32, 64);
    a6 += __shfl_xor(a6, 32, 64);
    a7 += __shfl_xor(a7, 32, 64);
    wsum += __shfl_xor(wsum, 32, 64);
    __syncthreads();
    if (t >= 64 && t < 96) {
        red[cg][0] = a0; red[cg][1] = a1; red[cg][2] = a2; red[cg][3] = a3;
        red[cg][4] = a4; red[cg][5] = a5; red[cg][6] = a6; red[cg][7] = a7;
        red[cg][8] = wsum;
    }
    __syncthreads();
    if (t < 32) {
        a0 += red[cg][0]; a1 += red[cg][1]; a2 += red[cg][2]; a3 += red[cg][3];
        a4 += red[cg][4]; a5 += red[cg][5]; a6 += red[cg][6]; a7 += red[cg][7];
        wsum += red[cg][8];
        float inv = 1.0f / wsum;
        const float4* bp = (const float4*)(b1 + cg * 8);
        float4 bb0 = bp[0], bb1 = bp[1];
        float o0 = fmaxf(a0 * inv + bb0.x, 0.f);
        float o1 = fmaxf(a1 * inv + bb0.y, 0.f);
        float o2 = fmaxf(a2 * inv + bb0.z, 0.f);
        float o3 = fmaxf(a3 * inv + bb0.w, 0.f);
        float o4 = fmaxf(a4 * inv + bb1.x, 0.f);
        float o5 = fmaxf(a5 * inv + bb1.y, 0.f);
        float o6 = fmaxf(a6 * inv + bb1.z, 0.f);
        float o7 = fmaxf(a7 * inv + bb1.w, 0.f);
        uint4 o;
        o.x = (unsigned int)f2b(o0) | ((unsigned int)f2b(o1) << 16);
        o.y = (unsigned int)f2b(o2) | ((unsigned int)f2b(o3) << 16);
        o.z = (unsigned int)f2b(o4) | ((unsigned int)f2b(o5) << 16);
        o.w = (unsigned int)f2b(o6) | ((unsigned int)f2b(o7) << 16);
        ((uint4*)(x2b + (size_t)v * 256))[cg] = o;
    }
}

// ---------------- GEMM2 (MFMA) + fused layer-2 logits ----------------------

__global__ __launch_bounds__(256) void k_gemm2(const unsigned short* __restrict__ Xb,
                                               const unsigned short* __restrict__ W2t,
                                               const float* __restrict__ asrc,
                                               const float* __restrict__ adst,
                                               unsigned short* __restrict__ h2b,
                                               float* __restrict__ als,
                                               float* __restrict__ ald, int n) {
    int t = threadIdx.x;
    int lane = t & 63, w = t >> 6;
    int lane15 = lane & 15, quad = lane >> 4;
    int row0 = blockIdx.x * 64 + w * 16;
    f32x4 acc = (f32x4)0.f;
#pragma unroll
    for (int k0 = 0; k0 < 256; k0 += 32) {
        short8 a = *(const short8*)&Xb[(size_t)(row0 + lane15) * 256 + k0 + quad * 8];
        short8 b = *(const short8*)&W2t[lane15 * 256 + k0 + quad * 8];
        acc = __builtin_amdgcn_mfma_f32_16x16x32_bf16(a, b, acc, 0, 0, 0);
    }
    float asv = asrc[lane15], adv = adst[lane15];
#pragma unroll
    for (int r = 0; r < 4; r++) {
        int row = row0 + quad * 4 + r;
        float hv = acc[r];
        float ps = hv * asv, pd = hv * adv;
#pragma unroll
        for (int off = 1; off < 16; off <<= 1) {
            ps += __shfl_xor(ps, off, 16);
            pd += __shfl_xor(pd, off, 16);
        }
        if (row < n) {
            h2b[(size_t)row * 16 + lane15] = f2b(hv);
            if (lane15 == 0) {
                als[row] = ps;
                ald[row] = pd;
            }
        }
    }
}

// ---------------- layer-2 aggregate (dword gather, 8 slots) + log_softmax ---

__global__ __launch_bounds__(256) void k_agg2(const int* __restrict__ csr,
                                              const int* __restrict__ offs,
                                              const float* __restrict__ als,
                                              const float* __restrict__ aldg,
                                              const unsigned short* __restrict__ h2b,
                                              const float* __restrict__ b2,
                                              float* __restrict__ out, int n) {
    int v = blockIdx.x * 4 + (threadIdx.x >> 6);
    if (v >= n) return;
    int lane = threadIdx.x & 63;
    int start = offs[v];
    int deg = offs[v + 1] - start;
    float aldv = aldg[v];
    int c2 = lane & 7;       // col pair: cols 2*c2, 2*c2+1
    int q = lane >> 3;       // edge slot 0..7
    const unsigned int* h2 = (const unsigned int*)h2b;   // row = 8 uints
    float acc0 = 0.f, acc1 = 0.f, wsum = 0.f;
    for (int e = q; e < deg; e += 8) {
        int u = csr[start + e];
        float x = als[u] + aldv;
        float wv = __expf(LRELU(x));
        unsigned int pk = h2[u * 8 + c2];
        acc0 += wv * bl(pk);
        acc1 += wv * bh(pk);
        wsum += wv;
    }
    // reduce over 8 edge slots (lane bits 3,4,5)
    acc0 += __shfl_xor(acc0, 32, 64);
    acc0 += __shfl_xor(acc0, 16, 64);
    acc0 += __shfl_xor(acc0, 8, 64);
    acc1 += __shfl_xor(acc1, 32, 64);
    acc1 += __shfl_xor(acc1, 16, 64);
    acc1 += __shfl_xor(acc1, 8, 64);
    wsum += __shfl_xor(wsum, 32, 64);
    wsum += __shfl_xor(wsum, 16, 64);
    wsum += __shfl_xor(wsum, 8, 64);
    float inv = 1.0f / wsum;
    float2 bb = ((const float2*)b2)[c2];
    float o0 = acc0 * inv + bb.x;
    float o1 = acc1 * inv + bb.y;
    // log_softmax over 16 cols held as 8 lanes x 2 cols (lane bits 0,1,2)
    float mx = fmaxf(o0, o1);
    mx = fmaxf(mx, __shfl_xor(mx, 1, 64));
    mx = fmaxf(mx, __shfl_xor(mx, 2, 64));
    mx = fmaxf(mx, __shfl_xor(mx, 4, 64));
    float s = __expf(o0 - mx) + __expf(o1 - mx);
    s += __shfl_xor(s, 1, 64);
    s += __shfl_xor(s, 2, 64);
    s += __shfl_xor(s, 4, 64);
    float l = mx + __logf(s);
    if (q == 0) {
        float2 r;
        r.x = o0 - l;
        r.y = o1 - l;
        ((float2*)out)[(size_t)v * 8 + c2] = r;
    }
}

// ---------------- launch ----------------

extern "C" void kernel_launch(void* const* d_in, const int* in_sizes, int n_in,
                              void* d_out, int out_size, void* d_ws, size_t ws_size,
                              hipStream_t stream) {
    const float* x = (const float*)d_in[0];
    const int* ei = (const int*)d_in[1];
    const float* W1 = (const float*)d_in[2];
    const float* asrc1 = (const float*)d_in[3];
    const float* adst1 = (const float*)d_in[4];
    const float* b1 = (const float*)d_in[5];
    const float* W2 = (const float*)d_in[6];
    const float* asrc2 = (const float*)d_in[7];
    const float* adst2 = (const float*)d_in[8];
    const float* b2 = (const float*)d_in[9];
    float* out = (float*)d_out;

    int n = in_sizes[0] / 256;   // 50000
    int E = in_sizes[1] / 2;     // 800000
    int P = E + n;
    const int* src = ei;
    const int* dst = ei + E;
    int NB = (n + 255) / 256;

    char* p = (char*)d_ws;
    auto alloc = [&](size_t bytes) {
        void* r = (void*)p;
        p += (bytes + 255) & ~(size_t)255;
        return r;
    };
    unsigned short* h1b = (unsigned short*)alloc((size_t)n * 256 * 2);
    unsigned short* x2b = (unsigned short*)alloc((size_t)n * 256 * 2);
    unsigned short* W1t = (unsigned short*)alloc((size_t)256 * 256 * 2);
    unsigned short* W2t = (unsigned short*)alloc((size_t)16 * 256 * 2);
    float* als1 = (float*)alloc((size_t)n * 8 * 4);
    float* ald1 = (float*)alloc((size_t)n * 8 * 4);
    unsigned short* h2b = (unsigned short*)alloc((size_t)n * 16 * 2);
    float* als2 = (float*)alloc((size_t)n * 4);
    float* ald2 = (float*)alloc((size_t)n * 4);
    int* deg = (int*)alloc((size_t)n * 4);
    int* offs = (int*)alloc((size_t)(n + 1) * 4);
    int* cursor = (int*)alloc((size_t)n * 4);
    int* stmp = (int*)alloc((size_t)n * 4);
    int* blocksum = (int*)alloc((size_t)NB * 4);
    int* blockpre = (int*)alloc((size_t)NB * 4);
    int* csr = (int*)alloc((size_t)P * 4);

    // CSR build
    hipMemsetAsync(deg, 0, (size_t)n * 4, stream);
    k_hist<<<(E + 255) / 256, 256, 0, stream>>>(dst, deg, E);
    k_scanA<<<NB, 256, 0, stream>>>(deg, stmp, blocksum, n);
    k_scanB<<<1, 256, 0, stream>>>(blocksum, blockpre, NB);
    k_scanC<<<NB, 256, 0, stream>>>(stmp, blockpre, offs, cursor, n, P);
    k_scatter<<<(P + 255) / 256, 256, 0, stream>>>(src, dst, cursor, csr, E, n);

    // layer 1
    k_prepw<<<272, 256, 0, stream>>>(W1, W2, W1t, W2t);
    k_gemm1<<<dim3((n + 127) / 128, 2), 256, 0, stream>>>(x, W1t, h1b, n);
    k_al1<<<(n + 3) / 4, 256, 0, stream>>>(h1b, asrc1, adst1, als1, ald1, n);
    k_agg1<<<n, 128, 0, stream>>>(csr, offs, als1, ald1, h1b, b1, x2b);

    // layer 2
    k_gemm2<<<(n + 63) / 64, 256, 0, stream>>>(x2b, W2t, asrc2, adst2, h2b, als2, ald2, n);
    k_agg2<<<(n + 3) / 4, 256, 0, stream>>>(csr, offs, als2, ald2, h2b, b2, out, n);
}

// Round 2
// 327.888 us; speedup vs baseline: 1.0422x; 1.0123x over previous
//
#include <hip/hip_runtime.h>
#include <hip/hip_bf16.h>

// GATNet v10: wave-per-node aggregation. k_agg1/k_agg2 restructured as 4
// independent waves per 256-thr block (one node each): no __syncthreads
// (wave-synchronous LDS with lgkmcnt fence), one fully-coalesced row per
// load instruction (512B), 4 rows in flight, per-lane-owned output columns
// (no cross-lane epilogue). Attacks the latency/phase-serialization that
// v9 exposed (VALU cut 60->41% with zero speedup => not VALU-bound).

#define LRELU(x) ((x) > 0.f ? (x) : 0.2f * (x))

typedef __attribute__((ext_vector_type(8))) short short8;
typedef __attribute__((ext_vector_type(8))) unsigned short ushort8;
typedef __attribute__((ext_vector_type(4))) float f32x4;

__device__ inline unsigned short f2b(float f) {
    __hip_bfloat16 h = __float2bfloat16(f);
    return *reinterpret_cast<unsigned short*>(&h);
}
__device__ inline float b2f(unsigned short u) {
    __hip_bfloat16 h;
    *reinterpret_cast<unsigned short*>(&h) = u;
    return __bfloat162float(h);
}
__device__ inline float bl(unsigned int u) { return __uint_as_float(u << 16); }
__device__ inline float bh(unsigned int u) { return __uint_as_float(u & 0xffff0000u); }

// ---------------- CSR build ----------------

__global__ void k_hist(const int* __restrict__ dst, int* deg, int E) {
    int i = blockIdx.x * blockDim.x + threadIdx.x;
    if (i < E) atomicAdd(&deg[dst[i]], 1);
}

__global__ __launch_bounds__(256) void k_scanA(const int* __restrict__ deg,
                                               int* __restrict__ tmp,
                                               int* __restrict__ blocksum, int n) {
    __shared__ int sc[256];
    int b = blockIdx.x, t = threadIdx.x;
    int i = b * 256 + t;
    int v = (i < n) ? deg[i] + 1 : 0;   // +1: self loop
    sc[t] = v;
    __syncthreads();
    for (int off = 1; off < 256; off <<= 1) {
        int x = 0;
        if (t >= off) x = sc[t - off];
        __syncthreads();
        sc[t] += x;
        __syncthreads();
    }
    if (i < n) tmp[i] = sc[t] - v;
    if (t == 255) blocksum[b] = sc[255];
}

__global__ __launch_bounds__(256) void k_scanB(const int* __restrict__ blocksum,
                                               int* __restrict__ blockpre, int nb) {
    __shared__ int sc[256];
    int t = threadIdx.x;
    int v = (t < nb) ? blocksum[t] : 0;
    sc[t] = v;
    __syncthreads();
    for (int off = 1; off < 256; off <<= 1) {
        int x = 0;
        if (t >= off) x = sc[t - off];
        __syncthreads();
        sc[t] += x;
        __syncthreads();
    }
    if (t < nb) blockpre[t] = sc[t] - v;
}

__global__ __launch_bounds__(256) void k_scanC(const int* __restrict__ tmp,
                                               const int* __restrict__ blockpre,
                                               int* __restrict__ offs,
                                               int* __restrict__ cursor, int n, int P) {
    int b = blockIdx.x, t = threadIdx.x;
    int i = b * 256 + t;
    if (i < n) {
        int o = tmp[i] + blockpre[b];
        offs[i] = o;
        cursor[i] = o;
    }
    if (i == 0) offs[n] = P;
}

__global__ void k_scatter(const int* __restrict__ src, const int* __restrict__ dst,
                          int* cursor, int* __restrict__ csr, int E, int n) {
    int i = blockIdx.x * blockDim.x + threadIdx.x;
    int s, d;
    if (i < E) {
        s = src[i];
        d = dst[i];
    } else if (i < E + n) {
        s = i - E;
        d = s;
    } else {
        return;
    }
    int p = atomicAdd(&cursor[d], 1);
    csr[p] = s;
}

// ---------------- weight prep: W1t[256][256], W2t[16][256] bf16 (merged) ----

__global__ __launch_bounds__(256) void k_prepw(const float* __restrict__ W1,
                                               const float* __restrict__ W2,
                                               unsigned short* __restrict__ W1t,
                                               unsigned short* __restrict__ W2t) {
    int b = blockIdx.x;
    if (b < 256) {
        int k = b, nn = threadIdx.x;
        W1t[nn * 256 + k] = f2b(W1[k * 256 + nn]);
    } else {
        int nn = b - 256, k = threadIdx.x;
        W2t[nn * 256 + k] = f2b(W2[k * 16 + nn]);
    }
}

// ---------------- GEMM1 (MFMA bf16): h1b[M,256] = bf16(A[M,256] @ W1) -------

__global__ __launch_bounds__(256) void k_gemm1(const float* __restrict__ A,
                                               const unsigned short* __restrict__ Wt,
                                               unsigned short* __restrict__ h1b, int M) {
    __shared__ unsigned short As[128][40];
    __shared__ unsigned short Bs[128][40];
    int t = threadIdx.x;
    int r0 = blockIdx.x * 128, c0 = blockIdx.y * 128;
    int srow = t >> 1, shalf = t & 1;
    int lane = t & 63, w = t >> 6;
    int lane15 = lane & 15, quad = lane >> 4;
    int rbw = (w & 1) * 64, cbw = (w >> 1) * 64;

    f32x4 acc[4][4];
#pragma unroll
    for (int i = 0; i < 4; i++)
#pragma unroll
        for (int j = 0; j < 4; j++) acc[i][j] = (f32x4)0.f;

    for (int k0 = 0; k0 < 256; k0 += 32) {
        {
            int row = r0 + srow;
            ushort8 p0, p1;
            if (row < M) {
                const float4* sp = (const float4*)&A[(size_t)row * 256 + k0 + shalf * 16];
                float4 f0 = sp[0], f1 = sp[1], f2 = sp[2], f3 = sp[3];
                p0[0] = f2b(f0.x); p0[1] = f2b(f0.y); p0[2] = f2b(f0.z); p0[3] = f2b(f0.w);
                p0[4] = f2b(f1.x); p0[5] = f2b(f1.y); p0[6] = f2b(f1.z); p0[7] = f2b(f1.w);
                p1[0] = f2b(f2.x); p1[1] = f2b(f2.y); p1[2] = f2b(f2.z); p1[3] = f2b(f2.w);
                p1[4] = f2b(f3.x); p1[5] = f2b(f3.y); p1[6] = f2b(f3.z); p1[7] = f2b(f3.w);
            } else {
                p0 = (ushort8)0; p1 = (ushort8)0;
            }
            *(ushort8*)&As[srow][shalf * 16] = p0;
            *(ushort8*)&As[srow][shalf * 16 + 8] = p1;
            const ushort8* bp = (const ushort8*)&Wt[(size_t)(c0 + srow) * 256 + k0 + shalf * 16];
            *(ushort8*)&Bs[srow][shalf * 16] = bp[0];
            *(ushort8*)&Bs[srow][shalf * 16 + 8] = bp[1];
        }
        __syncthreads();
        short8 af[4], bf[4];
#pragma unroll
        for (int i = 0; i < 4; i++)
            af[i] = *(const short8*)&As[rbw + i * 16 + lane15][quad * 8];
#pragma unroll
        for (int j = 0; j < 4; j++)
            bf[j] = *(const short8*)&Bs[cbw + j * 16 + lane15][quad * 8];
#pragma unroll
        for (int i = 0; i < 4; i++)
#pragma unroll
            for (int j = 0; j < 4; j++)
                acc[i][j] = __builtin_amdgcn_mfma_f32_16x16x32_bf16(af[i], bf[j], acc[i][j], 0, 0, 0);
        __syncthreads();
    }
#pragma unroll
    for (int i = 0; i < 4; i++) {
        int rowb = r0 + rbw + i * 16 + quad * 4;
#pragma unroll
        for (int j = 0; j < 4; j++) {
            int col = c0 + cbw + j * 16 + lane15;
#pragma unroll
            for (int r = 0; r < 4; r++) {
                int row = rowb + r;
                if (row < M) h1b[(size_t)row * 256 + col] = f2b(acc[i][j][r]);
            }
        }
    }
}

// ---------------- attention logits layer 1: wave per node, 4 nodes/block ----

__global__ __launch_bounds__(256) void k_al1(const unsigned short* __restrict__ h1b,
                                             const float* __restrict__ asrc,
                                             const float* __restrict__ adst,
                                             float* __restrict__ als,
                                             float* __restrict__ ald, int n) {
    int v = blockIdx.x * 4 + (threadIdx.x >> 6);
    if (v >= n) return;
    int lane = threadIdx.x & 63;
    const uint2* hp = (const uint2*)(h1b + (size_t)v * 256);
    uint2 pk = hp[lane];
    float f0 = bl(pk.x);
    float f1 = bh(pk.x);
    float f2 = bl(pk.y);
    float f3 = bh(pk.y);
    float4 a_s = ((const float4*)asrc)[lane];
    float4 a_d = ((const float4*)adst)[lane];
    float ps = f0 * a_s.x + f1 * a_s.y + f2 * a_s.z + f3 * a_s.w;
    float pd = f0 * a_d.x + f1 * a_d.y + f2 * a_d.z + f3 * a_d.w;
#pragma unroll
    for (int off = 1; off < 8; off <<= 1) {
        ps += __shfl_xor(ps, off, 64);
        pd += __shfl_xor(pd, off, 64);
    }
    if ((lane & 7) == 0) {
        int h = lane >> 3;
        als[v * 8 + h] = ps;
        ald[v * 8 + h] = pd;
    }
}

// ---------------- layer-1 aggregate: wave per node, no block barriers -------
// 256 thr = 4 independent waves, one node each. Lane owns cols [4L,4L+4).
// Phase A (all 64 lanes): edge e2=lane>>1, head-quad half=lane&1 -> w into
// LDS ws[e][8], su[e]. Wave-synchronous handoff (lgkmcnt fence, no barrier).
// Phase B: 4 rows/iter, each row = one fully-coalesced 512B wave load.
// Epilogue: pure per-lane (no shfl/LDS), uint2 store.

__global__ __launch_bounds__(256) void k_agg1(const int* __restrict__ csr,
                                              const int* __restrict__ offs,
                                              const float* __restrict__ als,
                                              const float* __restrict__ aldg,
                                              const unsigned short* __restrict__ h1b,
                                              const float* __restrict__ b1,
                                              unsigned short* __restrict__ x2b, int n) {
    int wid = threadIdx.x >> 6;
    int v = blockIdx.x * 4 + wid;
    if (v >= n) return;
    int lane = threadIdx.x & 63;
    int start = offs[v];
    int deg = offs[v + 1] - start;
    __shared__ int su_s[4][32];
    __shared__ float ws_s[4][32 * 8];
    int* su = su_s[wid];
    float* ws = ws_s[wid];
    int h = lane >> 3;                    // head for phase B (cols 4*lane..)
    int e2 = lane >> 1, half = lane & 1;  // phase A mapping
    float4 aldv4 = ((const float4*)(aldg + (size_t)v * 8))[half];
    float a0 = 0.f, a1 = 0.f, a2 = 0.f, a3 = 0.f, wsum = 0.f;
    for (int base = 0; base < deg; base += 32) {
        int cnt = min(32, deg - base);
        int cnt4 = (cnt + 3) & ~3;
        __builtin_amdgcn_wave_barrier();
        {
            int u = v;
            float4 w4 = make_float4(0.f, 0.f, 0.f, 0.f);
            if (e2 < cnt) {
                u = csr[start + base + e2];
                float4 x0 = ((const float4*)(als + (size_t)u * 8))[half];
                w4.x = __expf(LRELU(x0.x + aldv4.x));
                w4.y = __expf(LRELU(x0.y + aldv4.y));
                w4.z = __expf(LRELU(x0.z + aldv4.z));
                w4.w = __expf(LRELU(x0.w + aldv4.w));
            }
            if (half == 0) su[e2] = u;
            *(float4*)&ws[e2 * 8 + half * 4] = w4;
        }
        __builtin_amdgcn_wave_barrier();
        asm volatile("s_waitcnt lgkmcnt(0)" ::: "memory");
        __builtin_amdgcn_wave_barrier();
        for (int e = 0; e < cnt4; e += 4) {
            int u0 = su[e + 0], u1 = su[e + 1], u2 = su[e + 2], u3 = su[e + 3];
            float w0 = ws[(e + 0) * 8 + h];
            float w1 = ws[(e + 1) * 8 + h];
            float w2 = ws[(e + 2) * 8 + h];
            float w3 = ws[(e + 3) * 8 + h];
            uint2 p0 = ((const uint2*)(h1b + (size_t)u0 * 256))[lane];
            uint2 p1 = ((const uint2*)(h1b + (size_t)u1 * 256))[lane];
            uint2 p2 = ((const uint2*)(h1b + (size_t)u2 * 256))[lane];
            uint2 p3 = ((const uint2*)(h1b + (size_t)u3 * 256))[lane];
            a0 += w0 * bl(p0.x); a1 += w0 * bh(p0.x);
            a2 += w0 * bl(p0.y); a3 += w0 * bh(p0.y);
            a0 += w1 * bl(p1.x); a1 += w1 * bh(p1.x);
            a2 += w1 * bl(p1.y); a3 += w1 * bh(p1.y);
            a0 += w2 * bl(p2.x); a1 += w2 * bh(p2.x);
            a2 += w2 * bl(p2.y); a3 += w2 * bh(p2.y);
            a0 += w3 * bl(p3.x); a1 += w3 * bh(p3.x);
            a2 += w3 * bl(p3.y); a3 += w3 * bh(p3.y);
            wsum += (w0 + w1) + (w2 + w3);
        }
        __builtin_amdgcn_wave_barrier();
    }
    float inv = 1.0f / wsum;
    float4 bb = ((const float4*)b1)[lane];
    float o0 = fmaxf(a0 * inv + bb.x, 0.f);
    float o1 = fmaxf(a1 * inv + bb.y, 0.f);
    float o2 = fmaxf(a2 * inv + bb.z, 0.f);
    float o3 = fmaxf(a3 * inv + bb.w, 0.f);
    uint2 o;
    o.x = (unsigned int)f2b(o0) | ((unsigned int)f2b(o1) << 16);
    o.y = (unsigned int)f2b(o2) | ((unsigned int)f2b(o3) << 16);
    ((uint2*)(x2b + (size_t)v * 256))[lane] = o;
}

// ---------------- GEMM2 (MFMA) + fused layer-2 logits ----------------------

__global__ __launch_bounds__(256) void k_gemm2(const unsigned short* __restrict__ Xb,
                                               const unsigned short* __restrict__ W2t,
                                               const float* __restrict__ asrc,
                                               const float* __restrict__ adst,
                                               unsigned short* __restrict__ h2b,
                                               float* __restrict__ als,
                                               float* __restrict__ ald, int n) {
    int t = threadIdx.x;
    int lane = t & 63, w = t >> 6;
    int lane15 = lane & 15, quad = lane >> 4;
    int row0 = blockIdx.x * 64 + w * 16;
    f32x4 acc = (f32x4)0.f;
#pragma unroll
    for (int k0 = 0; k0 < 256; k0 += 32) {
        short8 a = *(const short8*)&Xb[(size_t)(row0 + lane15) * 256 + k0 + quad * 8];
        short8 b = *(const short8*)&W2t[lane15 * 256 + k0 + quad * 8];
        acc = __builtin_amdgcn_mfma_f32_16x16x32_bf16(a, b, acc, 0, 0, 0);
    }
    float asv = asrc[lane15], adv = adst[lane15];
#pragma unroll
    for (int r = 0; r < 4; r++) {
        int row = row0 + quad * 4 + r;
        float hv = acc[r];
        float ps = hv * asv, pd = hv * adv;
#pragma unroll
        for (int off = 1; off < 16; off <<= 1) {
            ps += __shfl_xor(ps, off, 16);
            pd += __shfl_xor(pd, off, 16);
        }
        if (row < n) {
            h2b[(size_t)row * 16 + lane15] = f2b(hv);
            if (lane15 == 0) {
                als[row] = ps;
                ald[row] = pd;
            }
        }
    }
}

// ---------------- layer-2 aggregate: wave per node + log_softmax ------------
// 64 lanes = 16 edge slots x 4 col-quads. Phase A: 1 exp per edge (was 8x
// redundant). Phase B: 16 rows/iter, uint2 per lane. Reduce over slots via
// 4 shfls; softmax across 4 lanes.

__global__ __launch_bounds__(256) void k_agg2(const int* __restrict__ csr,
                                              const int* __restrict__ offs,
                                              const float* __restrict__ als,
                                              const float* __restrict__ aldg,
                                              const unsigned short* __restrict__ h2b,
                                              const float* __restrict__ b2,
                                              float* __restrict__ out, int n) {
    int wid = threadIdx.x >> 6;
    int v = blockIdx.x * 4 + wid;
    if (v >= n) return;
    int lane = threadIdx.x & 63;
    int start = offs[v];
    int deg = offs[v + 1] - start;
    __shared__ int su_s[4][32];
    __shared__ float ws_s[4][32];
    int* su = su_s[wid];
    float* ws = ws_s[wid];
    float aldv = aldg[v];
    int e16 = lane >> 2, cq = lane & 3;
    float a0 = 0.f, a1 = 0.f, a2 = 0.f, a3 = 0.f, wsum = 0.f;
    for (int base = 0; base < deg; base += 32) {
        int cnt = min(32, deg - base);
        int cnt16 = (cnt + 15) & ~15;
        __builtin_amdgcn_wave_barrier();
        if (lane < 32) {
            int u = v;
            float wv = 0.f;
            if (lane < cnt) {
                u = csr[start + base + lane];
                float x = als[u] + aldv;
                wv = __expf(LRELU(x));
            }
            su[lane] = u;
            ws[lane] = wv;
        }
        __builtin_amdgcn_wave_barrier();
        asm volatile("s_waitcnt lgkmcnt(0)" ::: "memory");
        __builtin_amdgcn_wave_barrier();
        for (int e = 0; e < cnt16; e += 16) {
            int u = su[e + e16];
            float wv = ws[e + e16];
            uint2 pk = ((const uint2*)(h2b + (size_t)u * 16))[cq];
            a0 += wv * bl(pk.x); a1 += wv * bh(pk.x);
            a2 += wv * bl(pk.y); a3 += wv * bh(pk.y);
            wsum += wv;
        }
        __builtin_amdgcn_wave_barrier();
    }
    // reduce over 16 edge slots (lane bits 2..5)
#pragma unroll
    for (int off = 4; off < 64; off <<= 1) {
        a0 += __shfl_xor(a0, off, 64);
        a1 += __shfl_xor(a1, off, 64);
        a2 += __shfl_xor(a2, off, 64);
        a3 += __shfl_xor(a3, off, 64);
        wsum += __shfl_xor(wsum, off, 64);
    }
    float inv = 1.0f / wsum;
    float4 bb = ((const float4*)b2)[cq];
    float o0 = a0 * inv + bb.x;
    float o1 = a1 * inv + bb.y;
    float o2 = a2 * inv + bb.z;
    float o3 = a3 * inv + bb.w;
    // log_softmax over 16 cols held as 4 lanes (cq) x 4 cols
    float mx = fmaxf(fmaxf(o0, o1), fmaxf(o2, o3));
    mx = fmaxf(mx, __shfl_xor(mx, 1, 64));
    mx = fmaxf(mx, __shfl_xor(mx, 2, 64));
    float s = __expf(o0 - mx) + __expf(o1 - mx) + __expf(o2 - mx) + __expf(o3 - mx);
    s += __shfl_xor(s, 1, 64);
    s += __shfl_xor(s, 2, 64);
    float l = mx + __logf(s);
    if (e16 == 0) {
        float4 r;
        r.x = o0 - l;
        r.y = o1 - l;
        r.z = o2 - l;
        r.w = o3 - l;
        ((float4*)out)[(size_t)v * 4 + cq] = r;
    }
}

// ---------------- launch ----------------

extern "C" void kernel_launch(void* const* d_in, const int* in_sizes, int n_in,
                              void* d_out, int out_size, void* d_ws, size_t ws_size,
                              hipStream_t stream) {
    const float* x = (const float*)d_in[0];
    const int* ei = (const int*)d_in[1];
    const float* W1 = (const float*)d_in[2];
    const float* asrc1 = (const float*)d_in[3];
    const float* adst1 = (const float*)d_in[4];
    const float* b1 = (const float*)d_in[5];
    const float* W2 = (const float*)d_in[6];
    const float* asrc2 = (const float*)d_in[7];
    const float* adst2 = (const float*)d_in[8];
    const float* b2 = (const float*)d_in[9];
    float* out = (float*)d_out;

    int n = in_sizes[0] / 256;   // 50000
    int E = in_sizes[1] / 2;     // 800000
    int P = E + n;
    const int* src = ei;
    const int* dst = ei + E;
    int NB = (n + 255) / 256;

    char* p = (char*)d_ws;
    auto alloc = [&](size_t bytes) {
        void* r = (void*)p;
        p += (bytes + 255) & ~(size_t)255;
        return r;
    };
    unsigned short* h1b = (unsigned short*)alloc((size_t)n * 256 * 2);
    unsigned short* x2b = (unsigned short*)alloc((size_t)n * 256 * 2);
    unsigned short* W1t = (unsigned short*)alloc((size_t)256 * 256 * 2);
    unsigned short* W2t = (unsigned short*)alloc((size_t)16 * 256 * 2);
    float* als1 = (float*)alloc((size_t)n * 8 * 4);
    float* ald1 = (float*)alloc((size_t)n * 8 * 4);
    unsigned short* h2b = (unsigned short*)alloc((size_t)n * 16 * 2);
    float* als2 = (float*)alloc((size_t)n * 4);
    float* ald2 = (float*)alloc((size_t)n * 4);
    int* deg = (int*)alloc((size_t)n * 4);
    int* offs = (int*)alloc((size_t)(n + 1) * 4);
    int* cursor = (int*)alloc((size_t)n * 4);
    int* stmp = (int*)alloc((size_t)n * 4);
    int* blocksum = (int*)alloc((size_t)NB * 4);
    int* blockpre = (int*)alloc((size_t)NB * 4);
    int* csr = (int*)alloc((size_t)P * 4);

    // CSR build
    hipMemsetAsync(deg, 0, (size_t)n * 4, stream);
    k_hist<<<(E + 255) / 256, 256, 0, stream>>>(dst, deg, E);
    k_scanA<<<NB, 256, 0, stream>>>(deg, stmp, blocksum, n);
    k_scanB<<<1, 256, 0, stream>>>(blocksum, blockpre, NB);
    k_scanC<<<NB, 256, 0, stream>>>(stmp, blockpre, offs, cursor, n, P);
    k_scatter<<<(P + 255) / 256, 256, 0, stream>>>(src, dst, cursor, csr, E, n);

    // layer 1
    k_prepw<<<272, 256, 0, stream>>>(W1, W2, W1t, W2t);
    k_gemm1<<<dim3((n + 127) / 128, 2), 256, 0, stream>>>(x, W1t, h1b, n);
    k_al1<<<(n + 3) / 4, 256, 0, stream>>>(h1b, asrc1, adst1, als1, ald1, n);
    k_agg1<<<(n + 3) / 4, 256, 0, stream>>>(csr, offs, als1, ald1, h1b, b1, x2b, n);

    // layer 2
    k_gemm2<<<(n + 63) / 64, 256, 0, stream>>>(x2b, W2t, asrc2, adst2, h2b, als2, ald2, n);
    k_agg2<<<(n + 3) / 4, 256, 0, stream>>>(csr, offs, als2, ald2, h2b, b2, out, n);
}